// Round 1
// baseline (3000.753 us; speedup 1.0000x reference)
//
#include <hip/hip_runtime.h>

#define NLEVELS 16
#define TSIZE 131072
#define TMASK (TSIZE - 1)

// R-1 per level, as float, compile-time
__device__ const float RM1_TAB[16] = {
    15.f, 21.f, 29.f, 40.f, 54.f, 74.f, 101.f, 138.f,
    187.f, 255.f, 347.f, 471.f, 641.f, 871.f, 1183.f, 1607.f
};

__global__ __launch_bounds__(256) void lotd_fwd(
    const float* __restrict__ xs,
    const float* __restrict__ params,
    const int*   __restrict__ inds,
    float*       __restrict__ out,
    int N)
{
    const int g = blockIdx.x * 256 + threadIdx.x;
    const int n = g >> 4;          // point index
    if (n >= N) return;
    const int l = g & 15;          // level index

    const float rm1 = RM1_TAB[l];
    const int   rmax = (int)rm1;   // R-1

    // point data (lanes with same n broadcast from L1)
    const float x = xs[3 * n + 0];
    const float y = xs[3 * n + 1];
    const float z = xs[3 * n + 2];
    const int tree = inds[n];

    // pos = (x*0.5+0.5) * (R-1)
    const float px = (x * 0.5f + 0.5f) * rm1;
    const float py = (y * 0.5f + 0.5f) * rm1;
    const float pz = (z * 0.5f + 0.5f) * rm1;
    const float fx = floorf(px), fy = floorf(py), fz = floorf(pz);
    const float wx = px - fx, wy = py - fy, wz = pz - fz;
    const int ix = (int)fx, iy = (int)fy, iz = (int)fz;

    // clipped corner coords per dim
    const int x0 = min(max(ix, 0), rmax), x1 = min(max(ix + 1, 0), rmax);
    const int y0 = min(max(iy, 0), rmax), y1 = min(max(iy + 1, 0), rmax);
    const int z0 = min(max(iz, 0), rmax), z1 = min(max(iz + 1, 0), rmax);

    // per-dim hash components (uint32 wraparound, primes 1 / 2654435761 / 805459861)
    const unsigned hx0 = (unsigned)x0;
    const unsigned hx1 = (unsigned)x1;
    const unsigned hy0 = (unsigned)y0 * 2654435761u;
    const unsigned hy1 = (unsigned)y1 * 2654435761u;
    const unsigned hz0 = (unsigned)z0 * 805459861u;
    const unsigned hz1 = (unsigned)z1 * 805459861u;

    const float2* __restrict__ tbl =
        (const float2*)(params + (size_t)(tree * NLEVELS + l) * (TSIZE * 2));

    // 8 corner indices first (let all gathers issue together)
    const int i000 = (int)((hx0 ^ hy0 ^ hz0) & TMASK);
    const int i001 = (int)((hx0 ^ hy0 ^ hz1) & TMASK);
    const int i010 = (int)((hx0 ^ hy1 ^ hz0) & TMASK);
    const int i011 = (int)((hx0 ^ hy1 ^ hz1) & TMASK);
    const int i100 = (int)((hx1 ^ hy0 ^ hz0) & TMASK);
    const int i101 = (int)((hx1 ^ hy0 ^ hz1) & TMASK);
    const int i110 = (int)((hx1 ^ hy1 ^ hz0) & TMASK);
    const int i111 = (int)((hx1 ^ hy1 ^ hz1) & TMASK);

    const float2 f000 = tbl[i000];
    const float2 f001 = tbl[i001];
    const float2 f010 = tbl[i010];
    const float2 f011 = tbl[i011];
    const float2 f100 = tbl[i100];
    const float2 f101 = tbl[i101];
    const float2 f110 = tbl[i110];
    const float2 f111 = tbl[i111];

    const float wx0 = 1.f - wx, wy0 = 1.f - wy, wz0 = 1.f - wz;

    // OFFS order (i,j,k) with offs[d]=1 -> use w[d], else 1-w[d]
    const float w000 = wx0 * wy0 * wz0;
    const float w001 = wx0 * wy0 * wz;
    const float w010 = wx0 * wy  * wz0;
    const float w011 = wx0 * wy  * wz;
    const float w100 = wx  * wy0 * wz0;
    const float w101 = wx  * wy0 * wz;
    const float w110 = wx  * wy  * wz0;
    const float w111 = wx  * wy  * wz;

    float acc0 = 0.f, acc1 = 0.f;
    acc0 = fmaf(w000, f000.x, acc0); acc1 = fmaf(w000, f000.y, acc1);
    acc0 = fmaf(w001, f001.x, acc0); acc1 = fmaf(w001, f001.y, acc1);
    acc0 = fmaf(w010, f010.x, acc0); acc1 = fmaf(w010, f010.y, acc1);
    acc0 = fmaf(w011, f011.x, acc0); acc1 = fmaf(w011, f011.y, acc1);
    acc0 = fmaf(w100, f100.x, acc0); acc1 = fmaf(w100, f100.y, acc1);
    acc0 = fmaf(w101, f101.x, acc0); acc1 = fmaf(w101, f101.y, acc1);
    acc0 = fmaf(w110, f110.x, acc0); acc1 = fmaf(w110, f110.y, acc1);
    acc0 = fmaf(w111, f111.x, acc0); acc1 = fmaf(w111, f111.y, acc1);

    // out[n, l*2 + f], row length 32 floats -> float2 slot n*16 + l (coalesced)
    ((float2*)out)[(size_t)n * 16 + l] = make_float2(acc0, acc1);
}

extern "C" void kernel_launch(void* const* d_in, const int* in_sizes, int n_in,
                              void* d_out, int out_size, void* d_ws, size_t ws_size,
                              hipStream_t stream) {
    const float* xs     = (const float*)d_in[0];
    const float* params = (const float*)d_in[1];
    const int*   inds   = (const int*)d_in[2];
    float*       out    = (float*)d_out;

    const int N = in_sizes[0] / 3;
    const int total = N * NLEVELS;
    const int blocks = (total + 255) / 256;
    lotd_fwd<<<blocks, 256, 0, stream>>>(xs, params, inds, out, N);
}

// Round 2
// 1127.969 us; speedup vs baseline: 2.6603x; 2.6603x over previous
//
#include <hip/hip_runtime.h>

#define NLEVELS 16
#define TSIZE 131072
#define TMASK (TSIZE - 1)

__device__ __constant__ float RM1_TAB[16] = {
    15.f, 21.f, 29.f, 40.f, 54.f, 74.f, 101.f, 138.f,
    187.f, 255.f, 347.f, 471.f, 641.f, 871.f, 1183.f, 1607.f
};

// ---------------- bucketing by tree ----------------

__global__ __launch_bounds__(256) void k_hist(const int* __restrict__ inds, int N,
                                              unsigned* __restrict__ hist) {
    __shared__ unsigned h[8];
    if (threadIdx.x < 8) h[threadIdx.x] = 0;
    __syncthreads();
    for (int i = blockIdx.x * blockDim.x + threadIdx.x; i < N;
         i += gridDim.x * blockDim.x)
        atomicAdd(&h[inds[i] & 7], 1u);
    __syncthreads();
    if (threadIdx.x < 8) atomicAdd(&hist[threadIdx.x], h[threadIdx.x]);
}

__global__ void k_scan(const unsigned* __restrict__ hist, unsigned* __restrict__ cursor) {
    if (threadIdx.x == 0) {
        unsigned s = 0;
        for (int t = 0; t < 8; ++t) { cursor[t] = s; s += hist[t]; }
    }
}

// scatter points into tree-sorted order: sorted[pos] = {x,y,z, pack(n,tree)}
__global__ __launch_bounds__(256) void k_scatter(const float* __restrict__ xs,
                                                 const int* __restrict__ inds, int N,
                                                 unsigned* __restrict__ cursor,
                                                 float4* __restrict__ sorted) {
    __shared__ unsigned wcnt[4][8];
    __shared__ unsigned wbase[4][8];
    const int i = blockIdx.x * 256 + threadIdx.x;
    const bool valid = (i < N);
    int tree = 0; float x = 0.f, y = 0.f, z = 0.f;
    if (valid) {
        tree = inds[i] & 7;
        x = xs[3 * i + 0]; y = xs[3 * i + 1]; z = xs[3 * i + 2];
    }
    const int lane = threadIdx.x & 63;
    const int wave = threadIdx.x >> 6;
    unsigned rank = 0;
    #pragma unroll
    for (int t = 0; t < 8; ++t) {
        unsigned long long m = __ballot(valid && (tree == t));
        if (valid && (tree == t))
            rank = (unsigned)__popcll(m & ((1ull << lane) - 1ull));
        if (lane == 0) wcnt[wave][t] = (unsigned)__popcll(m);
    }
    __syncthreads();
    if (threadIdx.x < 8) {
        const int t = threadIdx.x;
        const unsigned c0 = wcnt[0][t], c1 = wcnt[1][t], c2 = wcnt[2][t], c3 = wcnt[3][t];
        const unsigned base = atomicAdd(&cursor[t], c0 + c1 + c2 + c3);
        wbase[0][t] = base;
        wbase[1][t] = base + c0;
        wbase[2][t] = base + c0 + c1;
        wbase[3][t] = base + c0 + c1 + c2;
    }
    __syncthreads();
    if (valid) {
        const unsigned pos = wbase[wave][tree] + rank;
        sorted[pos] = make_float4(x, y, z,
            __uint_as_float(((unsigned)i) | ((unsigned)tree << 24)));
    }
}

// ---------------- main gather kernel ----------------
// grid: x = span*8 (XCD-swizzled chunks), y = level-pair k (slowest)
// thread = one point, two levels (2k, 2k+1); per-XCD working set ~2 MB -> L2-resident

__global__ __launch_bounds__(256) void k_main(const float4* __restrict__ sorted,
                                              const float* __restrict__ params,
                                              float* __restrict__ out,
                                              int N, int span, int nc) {
    const unsigned j = blockIdx.x & 7u;         // XCD round-robin phase
    const unsigned local = blockIdx.x >> 3;
    const unsigned chunk = j * (unsigned)span + local;
    if (chunk >= (unsigned)nc) return;
    const int i = (int)chunk * 256 + threadIdx.x;
    if (i >= N) return;

    const float4 p = sorted[i];
    const unsigned wbits = __float_as_uint(p.w);
    const int n = (int)(wbits & 0xFFFFFFu);
    const int tree = (int)(wbits >> 24);
    const int k = blockIdx.y;                   // level pair

    float acc[4];

    #pragma unroll
    for (int kk = 0; kk < 2; ++kk) {
        const int l = 2 * k + kk;
        const float rm1 = RM1_TAB[l];
        const int rmax = (int)rm1;

        const float px = (p.x * 0.5f + 0.5f) * rm1;
        const float py = (p.y * 0.5f + 0.5f) * rm1;
        const float pz = (p.z * 0.5f + 0.5f) * rm1;
        const float fx = floorf(px), fy = floorf(py), fz = floorf(pz);
        const float wx = px - fx, wy = py - fy, wz = pz - fz;
        const int ix = (int)fx, iy = (int)fy, iz = (int)fz;

        const int x0 = min(max(ix, 0), rmax), x1 = min(max(ix + 1, 0), rmax);
        const int y0 = min(max(iy, 0), rmax), y1 = min(max(iy + 1, 0), rmax);
        const int z0 = min(max(iz, 0), rmax), z1 = min(max(iz + 1, 0), rmax);

        const unsigned hx0 = (unsigned)x0;
        const unsigned hx1 = (unsigned)x1;
        const unsigned hy0 = (unsigned)y0 * 2654435761u;
        const unsigned hy1 = (unsigned)y1 * 2654435761u;
        const unsigned hz0 = (unsigned)z0 * 805459861u;
        const unsigned hz1 = (unsigned)z1 * 805459861u;

        const float2* __restrict__ tbl =
            (const float2*)(params + (size_t)(tree * NLEVELS + l) * (TSIZE * 2));

        const int i000 = (int)((hx0 ^ hy0 ^ hz0) & TMASK);
        const int i001 = (int)((hx0 ^ hy0 ^ hz1) & TMASK);
        const int i010 = (int)((hx0 ^ hy1 ^ hz0) & TMASK);
        const int i011 = (int)((hx0 ^ hy1 ^ hz1) & TMASK);
        const int i100 = (int)((hx1 ^ hy0 ^ hz0) & TMASK);
        const int i101 = (int)((hx1 ^ hy0 ^ hz1) & TMASK);
        const int i110 = (int)((hx1 ^ hy1 ^ hz0) & TMASK);
        const int i111 = (int)((hx1 ^ hy1 ^ hz1) & TMASK);

        const float2 f000 = tbl[i000];
        const float2 f001 = tbl[i001];
        const float2 f010 = tbl[i010];
        const float2 f011 = tbl[i011];
        const float2 f100 = tbl[i100];
        const float2 f101 = tbl[i101];
        const float2 f110 = tbl[i110];
        const float2 f111 = tbl[i111];

        const float wx0 = 1.f - wx, wy0 = 1.f - wy, wz0 = 1.f - wz;

        const float w000 = wx0 * wy0 * wz0;
        const float w001 = wx0 * wy0 * wz;
        const float w010 = wx0 * wy  * wz0;
        const float w011 = wx0 * wy  * wz;
        const float w100 = wx  * wy0 * wz0;
        const float w101 = wx  * wy0 * wz;
        const float w110 = wx  * wy  * wz0;
        const float w111 = wx  * wy  * wz;

        float acc0 = 0.f, acc1 = 0.f;
        acc0 = fmaf(w000, f000.x, acc0); acc1 = fmaf(w000, f000.y, acc1);
        acc0 = fmaf(w001, f001.x, acc0); acc1 = fmaf(w001, f001.y, acc1);
        acc0 = fmaf(w010, f010.x, acc0); acc1 = fmaf(w010, f010.y, acc1);
        acc0 = fmaf(w011, f011.x, acc0); acc1 = fmaf(w011, f011.y, acc1);
        acc0 = fmaf(w100, f100.x, acc0); acc1 = fmaf(w100, f100.y, acc1);
        acc0 = fmaf(w101, f101.x, acc0); acc1 = fmaf(w101, f101.y, acc1);
        acc0 = fmaf(w110, f110.x, acc0); acc1 = fmaf(w110, f110.y, acc1);
        acc0 = fmaf(w111, f111.x, acc0); acc1 = fmaf(w111, f111.y, acc1);

        acc[2 * kk + 0] = acc0;
        acc[2 * kk + 1] = acc1;
    }

    // out floats [n*32 + 8k, n*32 + 8k + 4) = levels 2k,2k+1 -> float4 slot n*8+k
    ((float4*)out)[(size_t)n * 8 + k] = make_float4(acc[0], acc[1], acc[2], acc[3]);
}

// ---------------- fallback (round-1 fused kernel) ----------------

__global__ __launch_bounds__(256) void lotd_fwd_fused(
    const float* __restrict__ xs, const float* __restrict__ params,
    const int* __restrict__ inds, float* __restrict__ out, int N)
{
    const int g = blockIdx.x * 256 + threadIdx.x;
    const int n = g >> 4;
    if (n >= N) return;
    const int l = g & 15;
    const float rm1 = RM1_TAB[l];
    const int rmax = (int)rm1;
    const float x = xs[3 * n], y = xs[3 * n + 1], z = xs[3 * n + 2];
    const int tree = inds[n];
    const float px = (x * 0.5f + 0.5f) * rm1;
    const float py = (y * 0.5f + 0.5f) * rm1;
    const float pz = (z * 0.5f + 0.5f) * rm1;
    const float fx = floorf(px), fy = floorf(py), fz = floorf(pz);
    const float wx = px - fx, wy = py - fy, wz = pz - fz;
    const int ix = (int)fx, iy = (int)fy, iz = (int)fz;
    const int x0 = min(max(ix, 0), rmax), x1 = min(max(ix + 1, 0), rmax);
    const int y0 = min(max(iy, 0), rmax), y1 = min(max(iy + 1, 0), rmax);
    const int z0 = min(max(iz, 0), rmax), z1 = min(max(iz + 1, 0), rmax);
    const unsigned hx0 = (unsigned)x0, hx1 = (unsigned)x1;
    const unsigned hy0 = (unsigned)y0 * 2654435761u, hy1 = (unsigned)y1 * 2654435761u;
    const unsigned hz0 = (unsigned)z0 * 805459861u,  hz1 = (unsigned)z1 * 805459861u;
    const float2* tbl = (const float2*)(params + (size_t)(tree * NLEVELS + l) * (TSIZE * 2));
    const float2 f000 = tbl[(hx0 ^ hy0 ^ hz0) & TMASK];
    const float2 f001 = tbl[(hx0 ^ hy0 ^ hz1) & TMASK];
    const float2 f010 = tbl[(hx0 ^ hy1 ^ hz0) & TMASK];
    const float2 f011 = tbl[(hx0 ^ hy1 ^ hz1) & TMASK];
    const float2 f100 = tbl[(hx1 ^ hy0 ^ hz0) & TMASK];
    const float2 f101 = tbl[(hx1 ^ hy0 ^ hz1) & TMASK];
    const float2 f110 = tbl[(hx1 ^ hy1 ^ hz0) & TMASK];
    const float2 f111 = tbl[(hx1 ^ hy1 ^ hz1) & TMASK];
    const float wx0 = 1.f - wx, wy0 = 1.f - wy, wz0 = 1.f - wz;
    float a0 = 0.f, a1 = 0.f;
    a0 = fmaf(wx0*wy0*wz0, f000.x, a0); a1 = fmaf(wx0*wy0*wz0, f000.y, a1);
    a0 = fmaf(wx0*wy0*wz , f001.x, a0); a1 = fmaf(wx0*wy0*wz , f001.y, a1);
    a0 = fmaf(wx0*wy *wz0, f010.x, a0); a1 = fmaf(wx0*wy *wz0, f010.y, a1);
    a0 = fmaf(wx0*wy *wz , f011.x, a0); a1 = fmaf(wx0*wy *wz , f011.y, a1);
    a0 = fmaf(wx *wy0*wz0, f100.x, a0); a1 = fmaf(wx *wy0*wz0, f100.y, a1);
    a0 = fmaf(wx *wy0*wz , f101.x, a0); a1 = fmaf(wx *wy0*wz , f101.y, a1);
    a0 = fmaf(wx *wy *wz0, f110.x, a0); a1 = fmaf(wx *wy *wz0, f110.y, a1);
    a0 = fmaf(wx *wy *wz , f111.x, a0); a1 = fmaf(wx *wy *wz , f111.y, a1);
    ((float2*)out)[(size_t)n * 16 + l] = make_float2(a0, a1);
}

extern "C" void kernel_launch(void* const* d_in, const int* in_sizes, int n_in,
                              void* d_out, int out_size, void* d_ws, size_t ws_size,
                              hipStream_t stream) {
    const float* xs     = (const float*)d_in[0];
    const float* params = (const float*)d_in[1];
    const int*   inds   = (const int*)d_in[2];
    float*       out    = (float*)d_out;

    const int N = in_sizes[0] / 3;

    const size_t need = 256 + (size_t)N * 16;
    if (ws_size < need) {
        // fallback: fused one-pass kernel
        const int total = N * NLEVELS;
        lotd_fwd_fused<<<(total + 255) / 256, 256, 0, stream>>>(xs, params, inds, out, N);
        return;
    }

    unsigned* hist   = (unsigned*)d_ws;                    // [8]
    unsigned* cursor = (unsigned*)((char*)d_ws + 64);      // [8]
    float4*   sorted = (float4*)((char*)d_ws + 256);       // [N]

    hipMemsetAsync(hist, 0, 64, stream);

    k_hist<<<512, 256, 0, stream>>>(inds, N, hist);
    k_scan<<<1, 64, 0, stream>>>(hist, cursor);

    const int nc = (N + 255) / 256;
    k_scatter<<<nc, 256, 0, stream>>>(xs, inds, N, cursor, sorted);

    const int span = (nc + 7) / 8;
    dim3 grid(span * 8, 8);
    k_main<<<grid, 256, 0, stream>>>(sorted, params, out, N, span, nc);
}